// Round 1
// baseline (1056.207 us; speedup 1.0000x reference)
//
#include <hip/hip_runtime.h>
#include <hip/hip_bf16.h>

// ---------------------------------------------------------------------------
// ProjectedConjugatedCSPNet: LN -> edge MLP (gather+sinemb+2xGEMM+silu) ->
// scatter-mean -> node MLP (2xGEMM+silu) -> residual add.
// All GEMMs: bf16 MFMA 16x16x32, B pre-swizzled to fragment-linear order.
// ---------------------------------------------------------------------------

typedef __attribute__((ext_vector_type(8))) short bfrag;   // 8 bf16 = 4 VGPRs
typedef __attribute__((ext_vector_type(4))) float ffrag;   // 4 fp32 acc

#define DEVI __device__ __forceinline__

constexpr int N_NODES = 10000;
constexpr int N_EDGES = 200000;
constexpr int HD      = 512;    // hidden dim
constexpr int KE      = 1824;   // padded edge-K: 512 hi + 512 hj + 32 lat(pad) + 768 sinemb
constexpr int NT      = HD / 16; // 32 n-tiles of 16 cols

DEVI float silu_f(float v) { return v / (1.0f + __expf(-v)); }

DEVI ushort f2bf(float f) {
    unsigned u = __float_as_uint(f);
    unsigned r = (u + 0x7fffu + ((u >> 16) & 1u)) >> 16;
    return (ushort)r;
}

// ---------------- LayerNorm: node_features -> h (bf16) ----------------------
__global__ void ln_kernel(const float* __restrict__ x, const float* __restrict__ g,
                          const float* __restrict__ b, ushort* __restrict__ h) {
    __shared__ float wred[8];
    __shared__ float mb[2];
    int row = blockIdx.x;
    int t = threadIdx.x;              // 256 threads
    const float* xr = x + (size_t)row * HD;
    float x0 = xr[t], x1 = xr[t + 256];
    float s = x0 + x1, q = x0 * x0 + x1 * x1;
    for (int o = 32; o; o >>= 1) { s += __shfl_down(s, o); q += __shfl_down(q, o); }
    int w = t >> 6, l = t & 63;
    if (l == 0) { wred[w] = s; wred[w + 4] = q; }
    __syncthreads();
    if (t == 0) {
        float S = wred[0] + wred[1] + wred[2] + wred[3];
        float Q = wred[4] + wred[5] + wred[6] + wred[7];
        float m = S * (1.0f / HD);
        float v = Q * (1.0f / HD) - m * m;
        mb[0] = m; mb[1] = rsqrtf(v + 1e-5f);
    }
    __syncthreads();
    float m = mb[0], rs = mb[1];
    h[(size_t)row * HD + t]       = f2bf((x0 - m) * rs * g[t] + b[t]);
    h[(size_t)row * HD + t + 256] = f2bf((x1 - m) * rs * g[t + 256] + b[t + 256]);
}

// ------- Weight swizzle: W[K x 512] fp32 -> B-fragment-linear bf16 ----------
// dst frag layout: [((kk*NT + nn)*64 + lane)*8 + j] = W[32kk + 8*(lane>>4) + j][16nn + (lane&15)]
// mode 1 = W_e1 remap onto padded K=1824 layout (zero rows in lat pad).
__global__ void wswz_kernel(const float* __restrict__ W, ushort* __restrict__ dst,
                            int Kp, int mode) {
    int fid = blockIdx.x * blockDim.x + threadIdx.x;
    int total = (Kp / 32) * NT * 64;
    if (fid >= total) return;
    int l  = fid & 63;
    int nn = (fid >> 6) & 31;
    int kk = fid >> 11;
    int col = nn * 16 + (l & 15);
    int kb  = kk * 32 + (l >> 4) * 8;
    union { ushort u16[8]; uint4 u4; } v;
    for (int j = 0; j < 8; ++j) {
        int krow = kb + j;
        int src;
        if (mode == 1) {
            if (krow < 1024)      src = krow;            // hi | hj
            else if (krow < 1056) src = (krow - 1024) < 6 ? krow : -1;  // lat (pad->0)
            else                  src = krow - 26;       // sinemb: 1030 + (krow-1056)
        } else {
            src = krow;
        }
        float f = (src < 0) ? 0.0f : W[(size_t)src * HD + col];
        v.u16[j] = f2bf(f);
    }
    *(uint4*)(dst + (size_t)fid * 8) = v.u4;
}

// ---------------- agg/cnt -> bf16 (scatter-mean divide) ---------------------
__global__ void aggdiv_kernel(const float* __restrict__ agg, const float* __restrict__ cnt,
                              ushort* __restrict__ aggb) {
    int i = blockIdx.x * 256 + threadIdx.x;   // N_NODES*HD threads
    int row = i >> 9;
    float rc = 1.0f / fmaxf(cnt[row], 1.0f);
    aggb[i] = f2bf(agg[i] * rc);
}

__global__ void sentinel_kernel(float* o, int n) {
    int i = blockIdx.x * 256 + threadIdx.x;
    if (i < n) o[i] = 123456789.0f;
}

// ---------------- Unified MFMA GEMM (64 rows x 512 cols per block) ----------
// MODE 0: edge GEMM1  A = [gather(h,src) | gather(h,dst) | lat | sinemb], out = silu -> e1 bf16
// MODE 1: edge GEMM2  A = e1, epilogue = silu + atomic scatter into agg (+cnt)
// MODE 2: node GEMM1  A = [h | aggb], out = silu -> o1 bf16
// MODE 3: node GEMM2  A = o1, out = node_features + silu -> d_out fp32
template <int MODE>
__global__ __launch_bounds__(512, 2) void gemm_kernel(
    const ushort* __restrict__ Asrc1, const ushort* __restrict__ Asrc2,
    const ushort* __restrict__ Bswz,  const float* __restrict__ bias,
    ushort* __restrict__ outb,        float* __restrict__ outf,
    float* __restrict__ cnt,          const float* __restrict__ nf,
    const int* __restrict__ edge_index, const int* __restrict__ e2g,
    const float* __restrict__ lattices, const float* __restrict__ frac_diff,
    int KT) {

    __shared__ ushort At[64 * 32];
    __shared__ int   ssrc[64];
    __shared__ int   sdst[64];
    __shared__ float sfd[64 * 3];
    __shared__ float slat[64 * 6];

    const int t = threadIdx.x;        // 512 threads = 8 waves
    const int w = t >> 6;
    const int l = t & 63;
    const int q = l >> 4;
    const int ml = l & 15;
    const int blk = blockIdx.x;
    const int rowbase = blk * 64;

    if (MODE == 0 || MODE == 1) {
        if (t < 64) {
            int eid = rowbase + t;
            int s = edge_index[eid];
            ssrc[t] = s;
            if (MODE == 0) {
                sdst[t] = edge_index[N_EDGES + eid];
                int g = e2g[eid];
                for (int c = 0; c < 6; ++c) slat[t * 6 + c] = lattices[g * 6 + c];
                for (int c = 0; c < 3; ++c) sfd[t * 3 + c] = frac_diff[(size_t)eid * 3 + c];
            }
        }
        __syncthreads();
    }

    ffrag acc[4][4];
    for (int m = 0; m < 4; ++m)
        for (int n = 0; n < 4; ++n)
            acc[m][n] = (ffrag){0.0f, 0.0f, 0.0f, 0.0f};

    const int r  = t >> 3;            // staging row 0..63
    const int c0 = (t & 7) * 4;       // staging col 0..28 step 4

    for (int kk = 0; kk < KT; ++kk) {
        // ---- stage A tile [64 x 32] bf16 ----
        ushort4 vals;
        if (MODE == 0) {
            if (kk < 32) {
                const ushort* hp = Asrc1 + (size_t)((kk < 16) ? ssrc[r] : sdst[r]) * HD
                                   + (kk & 15) * 32 + c0;
                vals = *(const ushort4*)hp;
            } else if (kk == 32) {
                float f[4];
                for (int i = 0; i < 4; ++i) {
                    int c = c0 + i;
                    f[i] = (c < 6) ? slat[r * 6 + c] : 0.0f;
                }
                vals = make_ushort4(f2bf(f[0]), f2bf(f[1]), f2bf(f[2]), f2bf(f[3]));
            } else {
                float f[4];
                for (int i = 0; i < 4; ++i) {
                    int d = (kk - 33) * 32 + c0 + i;     // 0..767
                    bool isc = d >= 384;
                    int e = isc ? d - 384 : d;
                    int sdim = e >> 7;
                    int kfr  = e & 127;
                    float ang = 6.2831853071795864f * (float)kfr * sfd[r * 3 + sdim];
                    f[i] = isc ? __cosf(ang) : __sinf(ang);
                }
                vals = make_ushort4(f2bf(f[0]), f2bf(f[1]), f2bf(f[2]), f2bf(f[3]));
            }
        } else if (MODE == 1) {
            vals = *(const ushort4*)(Asrc1 + (size_t)(rowbase + r) * HD + kk * 32 + c0);
        } else if (MODE == 2) {
            int row = rowbase + r;
            if (row < N_NODES) {
                const ushort* p = (kk < 16)
                    ? (Asrc1 + (size_t)row * HD + kk * 32 + c0)
                    : (Asrc2 + (size_t)row * HD + (kk - 16) * 32 + c0);
                vals = *(const ushort4*)p;
            } else vals = make_ushort4(0, 0, 0, 0);
        } else {
            int row = rowbase + r;
            vals = (row < N_NODES)
                ? *(const ushort4*)(Asrc1 + (size_t)row * HD + kk * 32 + c0)
                : make_ushort4(0, 0, 0, 0);
        }
        *(ushort4*)&At[r * 32 + c0] = vals;
        __syncthreads();

        // ---- fragments + MFMA ----
        bfrag af[4];
        for (int m = 0; m < 4; ++m)
            af[m] = *(const bfrag*)&At[(16 * m + ml) * 32 + q * 8];
        bfrag bf_[4];
        const ushort* bp = Bswz + ((size_t)(kk * NT + (w << 2)) * 64 + l) * 8;
        for (int n = 0; n < 4; ++n)
            bf_[n] = *(const bfrag*)(bp + (size_t)n * 64 * 8);
        for (int m = 0; m < 4; ++m)
            for (int n = 0; n < 4; ++n)
                acc[m][n] = __builtin_amdgcn_mfma_f32_16x16x32_bf16(af[m], bf_[n], acc[m][n], 0, 0, 0);
        __syncthreads();
    }

    // ---- epilogue ----
    if (MODE == 1 && t < 64) unsafeAtomicAdd(&cnt[ssrc[t]], 1.0f);

    for (int n = 0; n < 4; ++n) {
        int cg = w * 64 + n * 16 + ml;
        float bv = bias[cg];
        for (int m = 0; m < 4; ++m) {
            for (int rr = 0; rr < 4; ++rr) {
                int rowl = 16 * m + 4 * q + rr;
                float v = silu_f(acc[m][n][rr] + bv);
                if (MODE == 0) {
                    outb[(size_t)(rowbase + rowl) * HD + cg] = f2bf(v);
                } else if (MODE == 1) {
                    unsafeAtomicAdd(&outf[(size_t)ssrc[rowl] * HD + cg], v);
                } else if (MODE == 2) {
                    int row = rowbase + rowl;
                    if (row < N_NODES) outb[(size_t)row * HD + cg] = f2bf(v);
                } else {
                    int row = rowbase + rowl;
                    if (row < N_NODES)
                        outf[(size_t)row * HD + cg] = nf[(size_t)row * HD + cg] + v;
                }
            }
        }
    }
}

// ---------------------------------------------------------------------------
extern "C" void kernel_launch(void* const* d_in, const int* in_sizes, int n_in,
                              void* d_out, int out_size, void* d_ws, size_t ws_size,
                              hipStream_t stream) {
    const float* nf      = (const float*)d_in[0];
    const float* latt    = (const float*)d_in[1];
    const int*   eidx    = (const int*)d_in[2];
    const int*   e2g     = (const int*)d_in[3];
    const float* fd      = (const float*)d_in[4];
    const float* ln_g    = (const float*)d_in[6];
    const float* ln_b    = (const float*)d_in[7];
    const float* W_e1    = (const float*)d_in[8];
    const float* b_e1    = (const float*)d_in[9];
    const float* W_e2    = (const float*)d_in[10];
    const float* b_e2    = (const float*)d_in[11];
    const float* W_n1    = (const float*)d_in[12];
    const float* b_n1    = (const float*)d_in[13];
    const float* W_n2    = (const float*)d_in[14];
    const float* b_n2    = (const float*)d_in[15];
    float* out = (float*)d_out;

    auto al = [](size_t x) { return (x + 511) & ~(size_t)511; };
    size_t off_h   = 0;                        size_t sz_h   = (size_t)N_NODES * HD * 2;
    size_t off_w1  = al(off_h + sz_h);         size_t sz_w1  = (size_t)KE * HD * 2;
    size_t off_w2  = al(off_w1 + sz_w1);       size_t sz_w2  = (size_t)HD * HD * 2;
    size_t off_wn1 = al(off_w2 + sz_w2);       size_t sz_wn1 = (size_t)2 * HD * HD * 2;
    size_t off_wn2 = al(off_wn1 + sz_wn1);     size_t sz_wn2 = (size_t)HD * HD * 2;
    size_t off_agg = al(off_wn2 + sz_wn2);     size_t sz_agg = (size_t)N_NODES * HD * 4;
    size_t off_cnt = al(off_agg + sz_agg);     size_t sz_cnt = (size_t)N_NODES * 4;
    size_t off_agb = al(off_cnt + sz_cnt);     size_t sz_agb = (size_t)N_NODES * HD * 2;
    size_t off_o1  = al(off_agb + sz_agb);     size_t sz_o1  = (size_t)N_NODES * HD * 2;
    size_t off_e1  = al(off_o1 + sz_o1);       size_t sz_e1  = (size_t)N_EDGES * HD * 2;
    size_t need    = off_e1 + sz_e1;

    if (ws_size < need) {
        sentinel_kernel<<<(out_size + 255) / 256, 256, 0, stream>>>(out, out_size);
        return;
    }

    char* ws = (char*)d_ws;
    ushort* h    = (ushort*)(ws + off_h);
    ushort* w1s  = (ushort*)(ws + off_w1);
    ushort* w2s  = (ushort*)(ws + off_w2);
    ushort* wn1s = (ushort*)(ws + off_wn1);
    ushort* wn2s = (ushort*)(ws + off_wn2);
    float*  agg  = (float*)(ws + off_agg);
    float*  cnt  = (float*)(ws + off_cnt);
    ushort* aggb = (ushort*)(ws + off_agb);
    ushort* o1   = (ushort*)(ws + off_o1);
    ushort* e1   = (ushort*)(ws + off_e1);

    // prep
    ln_kernel<<<N_NODES, 256, 0, stream>>>(nf, ln_g, ln_b, h);
    wswz_kernel<<<(KE / 32) * NT * 64 / 256, 256, 0, stream>>>(W_e1, w1s, KE, 1);
    wswz_kernel<<<(HD / 32) * NT * 64 / 256, 256, 0, stream>>>(W_e2, w2s, HD, 0);
    wswz_kernel<<<(2 * HD / 32) * NT * 64 / 256, 256, 0, stream>>>(W_n1, wn1s, 2 * HD, 0);
    wswz_kernel<<<(HD / 32) * NT * 64 / 256, 256, 0, stream>>>(W_n2, wn2s, HD, 0);
    hipMemsetAsync(agg, 0, sz_agg, stream);
    hipMemsetAsync(cnt, 0, sz_cnt, stream);

    // edge pipeline
    gemm_kernel<0><<<N_EDGES / 64, 512, 0, stream>>>(
        h, nullptr, w1s, b_e1, e1, nullptr, nullptr, nullptr,
        eidx, e2g, latt, fd, KE / 32);
    gemm_kernel<1><<<N_EDGES / 64, 512, 0, stream>>>(
        e1, nullptr, w2s, b_e2, nullptr, agg, cnt, nullptr,
        eidx, nullptr, nullptr, nullptr, HD / 32);

    // scatter-mean divide
    aggdiv_kernel<<<(N_NODES * HD) / 256, 256, 0, stream>>>(agg, cnt, aggb);

    // node pipeline
    int nblocks = (N_NODES + 63) / 64;
    gemm_kernel<2><<<nblocks, 512, 0, stream>>>(
        h, aggb, wn1s, b_n1, o1, nullptr, nullptr, nullptr,
        nullptr, nullptr, nullptr, nullptr, 2 * HD / 32);
    gemm_kernel<3><<<nblocks, 512, 0, stream>>>(
        o1, nullptr, wn2s, b_n2, nullptr, out, nullptr, nf,
        nullptr, nullptr, nullptr, nullptr, HD / 32);
}